// Round 1
// baseline (7636.628 us; speedup 1.0000x reference)
//
#include <hip/hip_runtime.h>

#define NB 2048     // batch
#define NT 10000    // time points
#define NH 64       // hidden width == wave size

__device__ __forceinline__ float readlane_f(float v, int l) {
    return __int_as_float(__builtin_amdgcn_readlane(__float_as_int(v), l));
}

__device__ __forceinline__ float fast_tanh_from_scaled(float pre_scaled) {
    // pre_scaled = 2*log2(e) * x  ->  tanh(x) = 1 - 2/(1 + e^{2x})
    float e = __builtin_amdgcn_exp2f(pre_scaled);
    return fmaf(-2.0f, __builtin_amdgcn_rcpf(1.0f + e), 1.0f);
}

__global__ __launch_bounds__(256, 2) void hybrid_euler_kernel(
    const float* __restrict__ z0in,
    const float* __restrict__ t,
    const float* __restrict__ prm,
    const float* __restrict__ W1,
    const float* __restrict__ b1,
    const float* __restrict__ W2,
    const float* __restrict__ b2,
    const float* __restrict__ W3,
    const float* __restrict__ b3,
    float* __restrict__ out)
{
    const int lane = threadIdx.x & 63;
    const int wid  = threadIdx.x >> 6;
    const int b    = (blockIdx.x << 2) + wid;    // trajectory index, one wave each

    const float S = 2.8853900817779268f;         // 2 * log2(e)

    // Per-lane constant weights (lane = hidden unit index).
    const float w1a = W1[lane]      * S;         // W1[0][lane], pre-scaled for tanh
    const float w1b = W1[64 + lane] * S;         // W1[1][lane]
    const float b1v = b1[lane]      * S;
    const float b2v = b2[lane]      * S;
    const float w3v = W3[lane];
    const float b3v = b3[0];
    const float kappa = prm[0];
    const float mass  = prm[2];
    const float kmoM  = -kappa / mass;           // mass == 1.0 -> exact

    // W2 column `lane` into 64 VGPRs (one-time strided load, L2-broadcast).
    float w2c[64];
    #pragma unroll
    for (int j = 0; j < 64; ++j) w2c[j] = W2[j * 64 + lane] * S;

    float z0 = z0in[b * 2 + 0];
    float z1 = z0in[b * 2 + 1];

    // Row 0 of the trajectory is the initial state.
    if (lane == 0) {
        *(float2*)(out + (size_t)b * 2) = make_float2(z0, z1);
    }

    float tprev = t[0];
    float* optr = out + (size_t)NB * 2 + (size_t)b * 2;   // row 1, this trajectory

    for (int s = 1; s < NT; ++s) {
        const float tcur = t[s];
        const float dt = tcur - tprev;
        tprev = tcur;

        // ---- layer 1: h1[lane] = tanh(z0*W1[0][lane] + z1*W1[1][lane] + b1) ----
        const float pre1 = fmaf(z0, w1a, fmaf(z1, w1b, b1v));
        const float h1 = fast_tanh_from_scaled(pre1);

        // ---- layer 2: h2[lane] = tanh(sum_j h1[j] * W2[j][lane] + b2[lane]) ----
        // readlane broadcast + fma; 4 accumulators to break the dependency chain
        float a0 = b2v, a1 = 0.0f, a2 = 0.0f, a3 = 0.0f;
        #pragma unroll
        for (int j = 0; j < 64; j += 4) {
            a0 = fmaf(readlane_f(h1, j + 0), w2c[j + 0], a0);
            a1 = fmaf(readlane_f(h1, j + 1), w2c[j + 1], a1);
            a2 = fmaf(readlane_f(h1, j + 2), w2c[j + 2], a2);
            a3 = fmaf(readlane_f(h1, j + 3), w2c[j + 3], a3);
        }
        const float pre2 = (a0 + a1) + (a2 + a3);
        const float h2 = fast_tanh_from_scaled(pre2);

        // ---- layer 3: nn = sum_k h2[k]*W3[k] + b3 (wave butterfly reduce) ----
        float pr = h2 * w3v;
        #pragma unroll
        for (int m = 1; m < 64; m <<= 1)
            pr += __shfl_xor(pr, m, 64);
        const float nn = pr + b3v;

        // ---- Euler update (z0n uses OLD z1, like the reference) ----
        const float z1n = fmaf(dt, fmaf(kmoM, z0, nn), z1);
        const float z0n = fmaf(dt, z1, z0);
        z0 = z0n; z1 = z1n;

        if (lane == 0) {
            *(float2*)optr = make_float2(z0, z1);
        }
        optr += (size_t)NB * 2;
    }
}

extern "C" void kernel_launch(void* const* d_in, const int* in_sizes, int n_in,
                              void* d_out, int out_size, void* d_ws, size_t ws_size,
                              hipStream_t stream) {
    const float* z0 = (const float*)d_in[0];
    const float* t  = (const float*)d_in[1];
    const float* pp = (const float*)d_in[2];
    const float* W1 = (const float*)d_in[3];
    const float* b1 = (const float*)d_in[4];
    const float* W2 = (const float*)d_in[5];
    const float* b2 = (const float*)d_in[6];
    const float* W3 = (const float*)d_in[7];
    const float* b3 = (const float*)d_in[8];
    float* out = (float*)d_out;

    hybrid_euler_kernel<<<dim3(NB / 4), dim3(256), 0, stream>>>(
        z0, t, pp, W1, b1, W2, b2, W3, b3, out);
}

// Round 3
// 5910.357 us; speedup vs baseline: 1.2921x; 1.2921x over previous
//
#include <hip/hip_runtime.h>

#define NB 2048     // batch
#define NT 10000    // time points
#define NH 64       // hidden width == wave size

typedef _Float16 half2_t __attribute__((ext_vector_type(2)));

__device__ __forceinline__ half2_t bch(int v) {
    return __builtin_bit_cast(half2_t, v);
}

__device__ __forceinline__ float fast_tanh_from_scaled(float pre_scaled) {
    // pre_scaled = 2*log2(e) * x  ->  tanh(x) = 1 - 2/(1 + e^{2x})
    float e = __builtin_amdgcn_exp2f(pre_scaled);
    return fmaf(-2.0f, __builtin_amdgcn_rcpf(1.0f + e), 1.0f);
}

__global__ __launch_bounds__(256, 2) void hybrid_euler_kernel(
    const float* __restrict__ z0in,
    const float* __restrict__ t,
    const float* __restrict__ prm,
    const float* __restrict__ W1,
    const float* __restrict__ b1,
    const float* __restrict__ W2,
    const float* __restrict__ b2,
    const float* __restrict__ W3,
    const float* __restrict__ b3,
    float* __restrict__ out)
{
    const int lane = threadIdx.x & 63;
    const int wid  = threadIdx.x >> 6;
    const int b    = (blockIdx.x << 2) + wid;    // trajectory index, one wave each

    const float S = 2.8853900817779268f;         // 2 * log2(e)

    // Per-lane constant weights (lane = hidden unit index).
    const float w1a = W1[lane]      * S;         // W1[0][lane], pre-scaled for tanh
    const float w1b = W1[64 + lane] * S;         // W1[1][lane]
    const float b1v = b1[lane]      * S;
    const float b2v = b2[lane]      * S;
    const float w3v = W3[lane];
    const float b3v = b3[0];
    const float kappa = prm[0];
    const float mass  = prm[2];
    const float kmoM  = -kappa / mass;

    // W2 column `lane`, rows packed in f16 pairs (2j, 2j+1): 32 VGPRs.
    // Pre-scaled by S so pre2 is ready for the exp2-based tanh.
    int w2pk[32];
    #pragma unroll
    for (int j = 0; j < 32; ++j) {
        float a = W2[(2 * j)     * 64 + lane] * S;
        float c = W2[(2 * j + 1) * 64 + lane] * S;
        half2_t p;
        p.x = (_Float16)a;     // RTN conversion
        p.y = (_Float16)c;
        w2pk[j] = __builtin_bit_cast(int, p);
    }
    // Opaque def point: compiler cannot rematerialize these from memory.
    #pragma unroll
    for (int j = 0; j < 32; ++j) asm volatile("" : "+v"(w2pk[j]));

    float z0 = z0in[b * 2 + 0];
    float z1 = z0in[b * 2 + 1];

    // Row 0 of the trajectory is the initial state.
    if (lane == 0) {
        *(float2*)(out + (size_t)b * 2) = make_float2(z0, z1);
    }

    float tprev = t[0];
    float tcur  = t[1];
    float* optr = out + (size_t)NB * 2 + (size_t)b * 2;   // row 1, this trajectory

    for (int s = 1; s < NT; ++s) {
        // Software-pipelined uniform t load (consumer is next iteration).
        const float tnext = (s + 1 < NT) ? t[s + 1] : tcur;
        const float dt = tcur - tprev;

        // ---- layer 1: h1[lane] = tanh(z0*W1[0][lane] + z1*W1[1][lane] + b1) ----
        const float pre1 = fmaf(z0, w1a, fmaf(z1, w1b, b1v));
        const float h1 = fast_tanh_from_scaled(pre1);

        // ---- pack h1 pairs: even lane 2j holds f16x2 (h1[2j], h1[2j+1]) ----
        const float h1n = __shfl_xor(h1, 1, 64);                 // DPP quad swap
        const int hpi = __builtin_bit_cast(int, __builtin_amdgcn_cvt_pkrtz(h1, h1n));

        // ---- layer 2: h2[lane] = tanh(sum_j h1[j] * W2[j][lane] + b2[lane]) ----
        // one readlane (pair broadcast) + one v_dot2_f32_f16 per 2 rows
        float a0 = b2v, a1 = 0.0f, a2 = 0.0f, a3 = 0.0f;
        #pragma unroll
        for (int j = 0; j < 32; j += 4) {
            a0 = __builtin_amdgcn_fdot2(bch(__builtin_amdgcn_readlane(hpi, 2 * (j + 0))), bch(w2pk[j + 0]), a0, false);
            a1 = __builtin_amdgcn_fdot2(bch(__builtin_amdgcn_readlane(hpi, 2 * (j + 1))), bch(w2pk[j + 1]), a1, false);
            a2 = __builtin_amdgcn_fdot2(bch(__builtin_amdgcn_readlane(hpi, 2 * (j + 2))), bch(w2pk[j + 2]), a2, false);
            a3 = __builtin_amdgcn_fdot2(bch(__builtin_amdgcn_readlane(hpi, 2 * (j + 3))), bch(w2pk[j + 3]), a3, false);
        }
        const float pre2 = (a0 + a1) + (a2 + a3);
        const float h2 = fast_tanh_from_scaled(pre2);

        // ---- layer 3: nn = sum_k h2[k]*W3[k] + b3 (wave butterfly all-reduce) ----
        float pr = h2 * w3v;
        #pragma unroll
        for (int m = 1; m < 64; m <<= 1)
            pr += __shfl_xor(pr, m, 64);
        const float nn = pr + b3v;

        // ---- Euler update (z0n uses OLD z1; z1n uses OLD z0) ----
        const float z1n = fmaf(dt, fmaf(kmoM, z0, nn), z1);
        const float z0n = fmaf(dt, z1, z0);
        z0 = z0n; z1 = z1n;

        if (lane == 0) {
            *(float2*)optr = make_float2(z0, z1);
        }
        optr += (size_t)NB * 2;

        tprev = tcur;
        tcur  = tnext;
    }
}

extern "C" void kernel_launch(void* const* d_in, const int* in_sizes, int n_in,
                              void* d_out, int out_size, void* d_ws, size_t ws_size,
                              hipStream_t stream) {
    const float* z0 = (const float*)d_in[0];
    const float* t  = (const float*)d_in[1];
    const float* pp = (const float*)d_in[2];
    const float* W1 = (const float*)d_in[3];
    const float* b1 = (const float*)d_in[4];
    const float* W2 = (const float*)d_in[5];
    const float* b2 = (const float*)d_in[6];
    const float* W3 = (const float*)d_in[7];
    const float* b3 = (const float*)d_in[8];
    float* out = (float*)d_out;

    hybrid_euler_kernel<<<dim3(NB / 4), dim3(256), 0, stream>>>(
        z0, t, pp, W1, b1, W2, b2, W3, b3, out);
}

// Round 5
// 4873.824 us; speedup vs baseline: 1.5669x; 1.2127x over previous
//
#include <hip/hip_runtime.h>

#define NB 2048     // batch
#define NT 10000    // time points

typedef _Float16 half2_t __attribute__((ext_vector_type(2)));

__device__ __forceinline__ half2_t bch(int v) {
    return __builtin_bit_cast(half2_t, v);
}

__device__ __forceinline__ float readlane_f(float v, int l) {
    return __int_as_float(__builtin_amdgcn_readlane(__float_as_int(v), l));
}

// DPP cross-lane (rows of 16): ~VALU-latency, no LDS pipe.
// ctrl must be an immediate -> template parameter.
template <int CTRL>
__device__ __forceinline__ float dpp_f(float x) {
    return __int_as_float(__builtin_amdgcn_mov_dpp(__float_as_int(x), CTRL, 0xF, 0xF, true));
}
#define DPP_XOR1 0xB1   // quad_perm [1,0,3,2]
#define DPP_XOR2 0x4E   // quad_perm [2,3,0,1]
#define DPP_HMIR 0x141  // row_half_mirror (combines quads within half-row)
#define DPP_MIR  0x140  // row_mirror      (combines half-rows)

__device__ __forceinline__ float fast_tanh_from_scaled(float pre_scaled) {
    // pre_scaled = 2*log2(e) * x  ->  tanh(x) = 1 - 2/(1 + e^{2x})
    float e = __builtin_amdgcn_exp2f(pre_scaled);
    return fmaf(-2.0f, __builtin_amdgcn_rcpf(1.0f + e), 1.0f);
}

__global__ __launch_bounds__(64, 2) void hybrid_euler_kernel(
    const float* __restrict__ z0in,
    const float* __restrict__ t,
    const float* __restrict__ prm,
    const float* __restrict__ W1,
    const float* __restrict__ b1,
    const float* __restrict__ W2,
    const float* __restrict__ b2,
    const float* __restrict__ W3,
    const float* __restrict__ b3,
    float* __restrict__ out)
{
    const int lane = threadIdx.x;        // one wave per block
    const int b    = blockIdx.x;         // trajectory index

    const float S = 2.8853900817779268f; // 2 * log2(e)

    const float w1a = W1[lane]      * S;
    const float w1b = W1[64 + lane] * S;
    const float b1v = b1[lane]      * S;
    const float b2v = b2[lane]      * S;
    const float w3v = W3[lane];
    const float b3v64 = b3[0] * 0.015625f;   // b3/64, folded into per-lane reduce
    const float kappa = prm[0];
    const float mass  = prm[2];
    const float kmoM  = -kappa / mass;

    // W2 column `lane`, rows packed in f16 pairs (2j, 2j+1): 32 regs, pre-scaled by S.
    int w2pk[32];
    #pragma unroll
    for (int j = 0; j < 32; ++j) {
        half2_t p;
        p.x = (_Float16)(W2[(2 * j)     * 64 + lane] * S);
        p.y = (_Float16)(W2[(2 * j + 1) * 64 + lane] * S);
        w2pk[j] = __builtin_bit_cast(int, p);
    }
    #pragma unroll
    for (int j = 0; j < 32; ++j) asm volatile("" : "+v"(w2pk[j]));

    float z0 = z0in[b * 2 + 0];
    float z1 = z0in[b * 2 + 1];

    if (lane == 0) {
        *(float2*)(out + (size_t)b * 2) = make_float2(z0, z1);
    }

    float tprev = t[0];
    float tcur  = t[1];
    float* optr = out + (size_t)NB * 2 + (size_t)b * 2;

    for (int s = 1; s < NT; ++s) {
        const float tnext = (s + 1 < NT) ? t[s + 1] : tcur;
        const float dt = tcur - tprev;

        // ---- layer 1 ----
        const float pre1 = fmaf(z0, w1a, fmaf(z1, w1b, b1v));
        const float h1 = fast_tanh_from_scaled(pre1);

        // ---- pack h1 pairs via DPP quad swap (even lane 2j: (h1[2j], h1[2j+1])) ----
        const float h1n = dpp_f<DPP_XOR1>(h1);
        const int hpi = __builtin_bit_cast(int, __builtin_amdgcn_cvt_pkrtz(h1, h1n));

        // ---- layer 2: 32 readlane-pair broadcasts + 32 dot2, 8 accumulator chains ----
        float ac[8];
        ac[0] = b2v;
        #pragma unroll
        for (int i = 1; i < 8; ++i) ac[i] = 0.0f;
        #pragma unroll
        for (int jo = 0; jo < 4; ++jo) {
            #pragma unroll
            for (int ji = 0; ji < 8; ++ji) {
                const int j = jo * 8 + ji;
                ac[ji] = __builtin_amdgcn_fdot2(
                    bch(__builtin_amdgcn_readlane(hpi, 2 * j)),
                    bch(w2pk[j]), ac[ji], false);
            }
        }
        const float pre2 = ((ac[0] + ac[1]) + (ac[2] + ac[3]))
                         + ((ac[4] + ac[5]) + (ac[6] + ac[7]));
        const float h2 = fast_tanh_from_scaled(pre2);

        // ---- layer 3: row-of-16 DPP reduce, then 4 readlanes ----
        float pr = fmaf(h2, w3v, b3v64);
        pr += dpp_f<DPP_XOR1>(pr);
        pr += dpp_f<DPP_XOR2>(pr);
        pr += dpp_f<DPP_HMIR>(pr);
        pr += dpp_f<DPP_MIR>(pr);
        const float r0  = readlane_f(pr, 0);
        const float r16 = readlane_f(pr, 16);
        const float r32 = readlane_f(pr, 32);
        const float r48 = readlane_f(pr, 48);
        const float nn = (r0 + r16) + (r32 + r48);

        // ---- Euler update (z0n uses OLD z1; z1n uses OLD z0) ----
        const float z1n = fmaf(dt, fmaf(kmoM, z0, nn), z1);
        const float z0n = fmaf(dt, z1, z0);
        z0 = z0n; z1 = z1n;

        if (lane == 0) {
            *(float2*)optr = make_float2(z0, z1);
        }
        optr += (size_t)NB * 2;

        tprev = tcur;
        tcur  = tnext;
    }
}

extern "C" void kernel_launch(void* const* d_in, const int* in_sizes, int n_in,
                              void* d_out, int out_size, void* d_ws, size_t ws_size,
                              hipStream_t stream) {
    const float* z0 = (const float*)d_in[0];
    const float* t  = (const float*)d_in[1];
    const float* pp = (const float*)d_in[2];
    const float* W1 = (const float*)d_in[3];
    const float* b1 = (const float*)d_in[4];
    const float* W2 = (const float*)d_in[5];
    const float* b2 = (const float*)d_in[6];
    const float* W3 = (const float*)d_in[7];
    const float* b3 = (const float*)d_in[8];
    float* out = (float*)d_out;

    hybrid_euler_kernel<<<dim3(NB), dim3(64), 0, stream>>>(
        z0, t, pp, W1, b1, W2, b2, W3, b3, out);
}